// Round 3
// baseline (401.322 us; speedup 1.0000x reference)
//
#include <hip/hip_runtime.h>

// LIF bitshift-decay scan: B=32, T=1024, N=1024, n_syn=2. fp32, bit-exact.
//
// R1 (register prefetch) and R2 (global_load_lds DMA) both hit 393 us =
// 460 cycles *per 256B load*, i.e. ~zero memory-level parallelism from a
// single dependent wave. R3 restructures for TLP-driven MLP:
//   - 512 blocks x 256 threads: wave 0 = consumer (64 sequential scans),
//     waves 1-3 = loaders streaming input global->VGPR->LDS.
//   - 32-step chunks, LDS double buffer (2 x 16 KB), 1 barrier per chunk.
//   - Loader loads are fully independent -> ~21 outstanding loads/wave,
//     ~33 KB in flight per CU at burst (need ~9 KB for 6.3 TB/s).
//   - Consumer stores chunk k's spikes at top of chunk k+1 so the implicit
//     vmcnt(0)-before-barrier drains them after a full chunk of overlap.
//
// Numerics: identical expression order to the verified-bit-exact R1 kernel.

#define TT 1024
#define NN 1024
#define BB 32
#define CH 32              // time-steps per chunk
#define NCH (TT / CH)      // 32 chunks
#define NROW (CH * 2)      // 64 rows (t,s) per chunk, 256 B each

__global__ __launch_bounds__(256, 1)
void lif_scan_kernel(const float* __restrict__ in, float* __restrict__ out) {
    __shared__ float sbuf[2][CH][2][64];   // [buf][t][syn][lane] = 32 KB

    const int tid  = threadIdx.x;
    const int wave = tid >> 6;
    const int lane = tid & 63;
    const int b    = blockIdx.x >> 4;        // 32 batches
    const int n0   = (blockIdx.x & 15) << 6; // 16 groups of 64 neurons

    // input:  (t*2 + s)*N + n  relative to batch base
    const float* gin  = in  + (size_t)b * TT * 2 * NN + n0;
    float*       gout = out + (size_t)b * TT * NN     + n0;

    if (wave == 0) {
        // ---------------- consumer: 64 sequential LIF scans ----------------
        const float SD0 = 0.25f;   // 2^-2 (tau_syn=5)
        const float SD1 = 0.5f;    // 2^-1 (tau_syn=2)
        const float MD  = 0.125f;  // 2^-3 (tau_mem=10)
        float i0 = 0.0f, i1 = 0.0f, v = 0.0f;
        float spk[CH];

        __syncthreads();   // chunk 0 staged by loaders

        for (int c = 0; c < NCH; ++c) {
            // store previous chunk's spikes (overlaps with this chunk's compute)
            if (c > 0) {
                float* go = gout + (size_t)(c - 1) * CH * NN + lane;
#pragma unroll
                for (int j = 0; j < CH; ++j) go[j * NN] = spk[j];
            }
            const int p = c & 1;
#pragma unroll
            for (int j = 0; j < CH; ++j) {
                float x0 = sbuf[p][j][0][lane];
                float x1 = sbuf[p][j][1][lane];
                i0 = (i0 - i0 * SD0) + x0;
                i1 = (i1 - i1 * SD1) + x1;
                float vd = v - v * MD;
                v = vd + (i0 + i1);
                float s_ = (v >= 1.0f) ? 1.0f : 0.0f;
                v -= s_;                 // membrane-subtract reset (thr=1.0)
                spk[j] = s_;
            }
            __syncthreads();
        }
        // final chunk's spikes
        float* go = gout + (size_t)(NCH - 1) * CH * NN + lane;
#pragma unroll
        for (int j = 0; j < CH; ++j) go[j * NN] = spk[j];

    } else {
        // ---------------- loaders: waves 1..3 stream input ----------------
        // row r (0..63) of a chunk: t-in-chunk j = r>>1, syn s = r&1.
        // loader li handles rows r == li (mod 3): 22/21/21 rows.
        const int li = wave - 1;
        float vbuf[22];

        // prologue: stage chunk 0 into buffer 0
        {
#pragma unroll
            for (int m = 0; m < 22; ++m) {
                int r = m * 3 + li;
                if (r < NROW)
                    vbuf[m] = gin[(size_t)(r >> 1) * 2048 + (r & 1) * 1024 + lane];
            }
#pragma unroll
            for (int m = 0; m < 22; ++m) {
                int r = m * 3 + li;
                if (r < NROW) sbuf[0][r >> 1][r & 1][lane] = vbuf[m];
            }
        }
        __syncthreads();

        for (int c = 0; c < NCH; ++c) {
            if (c + 1 < NCH) {
                const float* gc = gin + (size_t)(c + 1) * CH * 2048;
                const int p = (c + 1) & 1;
#pragma unroll
                for (int m = 0; m < 22; ++m) {
                    int r = m * 3 + li;
                    if (r < NROW)
                        vbuf[m] = gc[(size_t)(r >> 1) * 2048 + (r & 1) * 1024 + lane];
                }
#pragma unroll
                for (int m = 0; m < 22; ++m) {
                    int r = m * 3 + li;
                    if (r < NROW) sbuf[p][r >> 1][r & 1][lane] = vbuf[m];
                }
            }
            __syncthreads();
        }
    }
}

extern "C" void kernel_launch(void* const* d_in, const int* in_sizes, int n_in,
                              void* d_out, int out_size, void* d_ws, size_t ws_size,
                              hipStream_t stream) {
    const float* in = (const float*)d_in[0];
    float* out = (float*)d_out;
    dim3 grid(BB * NN / 64);   // 512 blocks, 64 neurons each
    dim3 block(256);           // wave 0 consumer + 3 loader waves
    hipLaunchKernelGGL(lif_scan_kernel, grid, block, 0, stream, in, out);
}